// Round 1
// baseline (1843.409 us; speedup 1.0000x reference)
//
#include <hip/hip_runtime.h>

// Problem constants
#define CDIM 384
#define NHEADS 8
#define HDIM 48
#define HH 56
#define WW 56
#define NPIX 3136        // 56*56
#define BB 8
#define CMID 1536
#define BN_EPS 1e-5f
#define LN_EPS 1e-5f

// ---------------------------------------------------------------------------
// Activation helpers
// ---------------------------------------------------------------------------
__device__ __forceinline__ float phi_act(float v) {
    // exp(GAMMA*(2v - v^2)), GAMMA=0.5
    return expf(0.5f * (2.f * v - v * v));
}
__device__ __forceinline__ float gelu_act(float v) {
    return 0.5f * v * (1.f + erff(v * 0.7071067811865476f));
}

// ---------------------------------------------------------------------------
// Generic fp32 GEMM: Out[i][j] = act( sum_k A[i,k]*B[k,j] + bias ) (+ Res)
// 64x64 tile, BK=16, 256 threads, 4x4 per thread.
// BIAS_MODE: 0 none, 1 per-row(i), 2 per-col(j). ACT: 0 none, 1 phi, 2 gelu.
// blockIdx.z batches B/C/Res by the given strides (A shared).
// All dims must be multiples of tile sizes (true for this problem).
// ---------------------------------------------------------------------------
template<int ACT, int BIAS_MODE, bool HAS_RES>
__global__ __launch_bounds__(256) void gemm64(
    const float* __restrict__ A, const float* __restrict__ Bm,
    float* __restrict__ Cm, const float* __restrict__ Res,
    const float* __restrict__ bias,
    long strideB, long strideC, long strideR,
    int K, int lda, int ldb, int ldc)
{
    const int z = blockIdx.z;
    Bm += (long)z * strideB;
    Cm += (long)z * strideC;
    if (HAS_RES) Res += (long)z * strideR;

    __shared__ float As[16][68];   // [k][m], padded
    __shared__ float Bs[16][64];   // [k][n]

    const int m0 = blockIdx.y * 64, n0 = blockIdx.x * 64;
    const int t  = threadIdx.x;
    const int tx = t & 15, ty = t >> 4;
    const int mA = t >> 2,  kA = (t & 3) << 2;   // A tile: 64 m x 16 k
    const int kB = t >> 4,  nB = (t & 15) << 2;  // B tile: 16 k x 64 n

    float acc[4][4] = {};

    for (int k0 = 0; k0 < K; k0 += 16) {
        const float4 a4 = *(const float4*)(A  + (long)(m0 + mA) * lda + k0 + kA);
        const float4 b4 = *(const float4*)(Bm + (long)(k0 + kB) * ldb + n0 + nB);
        __syncthreads();   // protect LDS from previous iteration's readers
        As[kA + 0][mA] = a4.x; As[kA + 1][mA] = a4.y;
        As[kA + 2][mA] = a4.z; As[kA + 3][mA] = a4.w;
        *(float4*)&Bs[kB][nB] = b4;
        __syncthreads();
        #pragma unroll
        for (int kk = 0; kk < 16; kk++) {
            const float4 av = *(const float4*)&As[kk][ty << 2];
            const float4 bv = *(const float4*)&Bs[kk][tx << 2];
            const float a_[4] = {av.x, av.y, av.z, av.w};
            const float b_[4] = {bv.x, bv.y, bv.z, bv.w};
            #pragma unroll
            for (int i = 0; i < 4; i++)
                #pragma unroll
                for (int j = 0; j < 4; j++)
                    acc[i][j] = fmaf(a_[i], b_[j], acc[i][j]);
        }
    }

    #pragma unroll
    for (int i = 0; i < 4; i++) {
        const int m = m0 + (ty << 2) + i;
        const long off = (long)m * ldc + n0 + (tx << 2);
        const float br = (BIAS_MODE == 1) ? bias[m] : 0.f;
        #pragma unroll
        for (int j = 0; j < 4; j++) {
            float v = acc[i][j];
            if (BIAS_MODE == 1) v += br;
            else if (BIAS_MODE == 2) v += bias[n0 + (tx << 2) + j];
            if (ACT == 1) v = phi_act(v);
            else if (ACT == 2) v = gelu_act(v);
            if (HAS_RES) v += Res[off + j];
            Cm[off + j] = v;
        }
    }
}

// ---------------------------------------------------------------------------
// Depthwise 3x3 SAME conv (cross-correlation, per-channel). One block per
// (b,c) plane; no bias (folded into BN2 downstream).
// ---------------------------------------------------------------------------
__global__ __launch_bounds__(256) void dwconv(const float* __restrict__ in,
                                              const float* __restrict__ w9,
                                              float* __restrict__ out)
{
    const int bc = blockIdx.x;
    const int c  = bc % CDIM;
    const float* ip = in  + (long)bc * NPIX;
    float*       op = out + (long)bc * NPIX;
    float w[9];
    #pragma unroll
    for (int i = 0; i < 9; i++) w[i] = w9[c * 9 + i];
    for (int p = threadIdx.x; p < NPIX; p += 256) {
        const int y = p / WW, x = p % WW;
        float acc = 0.f;
        #pragma unroll
        for (int r = 0; r < 3; r++) {
            const int yy = y + r - 1;
            if ((unsigned)yy >= HH) continue;
            #pragma unroll
            for (int s = 0; s < 3; s++) {
                const int xx = x + s - 1;
                if ((unsigned)xx >= WW) continue;
                acc = fmaf(ip[yy * WW + xx], w[r * 3 + s], acc);
            }
        }
        op[p] = acc;
    }
}

// ---------------------------------------------------------------------------
// BN folding prep: s/t per channel for BN1 and BN2 (db folded into t2).
// ---------------------------------------------------------------------------
__global__ void prep_bn_k(const float* __restrict__ w1, const float* __restrict__ b1,
                          const float* __restrict__ m1, const float* __restrict__ v1,
                          const float* __restrict__ w2, const float* __restrict__ b2,
                          const float* __restrict__ m2, const float* __restrict__ v2,
                          const float* __restrict__ db,
                          float* s1, float* t1, float* s2, float* t2)
{
    const int i = threadIdx.x;
    if (i < CDIM) {
        const float a = w1[i] * rsqrtf(v1[i] + BN_EPS);
        s1[i] = a; t1[i] = b1[i] - m1[i] * a;
        const float c = w2[i] * rsqrtf(v2[i] + BN_EPS);
        s2[i] = c; t2[i] = b2[i] - m2[i] * c + db[i] * c;
    }
}

// Effective conv weights/biases: we[o,i] = cw[o,i]*s[i]; be[o] = cb[o]+sum cw[o,i]*t[i]
__global__ __launch_bounds__(64) void prep_w_k(
    const float* __restrict__ cw1, const float* __restrict__ cb1,
    const float* __restrict__ cw2, const float* __restrict__ cb2,
    const float* __restrict__ s1, const float* __restrict__ t1,
    const float* __restrict__ s2, const float* __restrict__ t2,
    float* __restrict__ w1e, float* __restrict__ b1e,
    float* __restrict__ w2e, float* __restrict__ b2e)
{
    const int o = blockIdx.x;
    const bool sec = (o >= CDIM);
    const int oo = sec ? o - CDIM : o;
    const float* cw = sec ? cw2 : cw1;
    const float* cb = sec ? cb2 : cb1;
    const float* s  = sec ? s2  : s1;
    const float* tt = sec ? t2  : t1;
    float* we = sec ? w2e : w1e;
    float* be = sec ? b2e : b1e;
    float part = 0.f;
    for (int i = threadIdx.x; i < CDIM; i += 64) {
        const float wv = cw[oo * CDIM + i];
        we[oo * CDIM + i] = wv * s[i];
        part += wv * tt[i];
    }
    for (int off = 32; off; off >>= 1) part += __shfl_down(part, off);
    if (threadIdx.x == 0) be[oo] = cb[oo] + part;
}

// ---------------------------------------------------------------------------
// Attention stats: kv[bh][d][e] = sum_n kp[n,d]*v[n,e]; ksum[bh][d] = sum_n kp[n,d]
// grid = (8 n-splits, 64 bh). 3x3 register block per thread, atomicAdd finish.
// ---------------------------------------------------------------------------
__global__ __launch_bounds__(256) void attn_kv_k(const float* __restrict__ kpb,
                                                 const float* __restrict__ vb,
                                                 float* __restrict__ kv,
                                                 float* __restrict__ ksum)
{
    const int s  = blockIdx.x;
    const int bh = blockIdx.y;
    const int b = bh >> 3, h = bh & 7;
    const float* kp = kpb + (long)b * CDIM * NPIX + (long)h * HDIM * NPIX;
    const float* vv = vb  + (long)b * CDIM * NPIX + (long)h * HDIM * NPIX;
    __shared__ float kt[HDIM * 68];
    __shared__ float vt[HDIM * 68];
    const int t = threadIdx.x;
    const int dg = t >> 4, eg = t & 15;     // d = dg*3+i, e = eg*3+j
    float acc[3][3] = {};
    float ks[3] = {0.f, 0.f, 0.f};
    for (int tl = s; tl < 49; tl += 8) {
        const int n0 = tl << 6;
        __syncthreads();
        for (int idx = t; idx < HDIM * 64; idx += 256) {
            const int d = idx >> 6, nn = idx & 63;
            kt[d * 68 + nn] = kp[(long)d * NPIX + n0 + nn];
            vt[d * 68 + nn] = vv[(long)d * NPIX + n0 + nn];
        }
        __syncthreads();
        for (int q4 = 0; q4 < 16; q4++) {
            float4 ka[3], va[3];
            #pragma unroll
            for (int i = 0; i < 3; i++) ka[i] = *(const float4*)&kt[(dg * 3 + i) * 68 + (q4 << 2)];
            #pragma unroll
            for (int j = 0; j < 3; j++) va[j] = *(const float4*)&vt[(eg * 3 + j) * 68 + (q4 << 2)];
            #pragma unroll
            for (int i = 0; i < 3; i++)
                #pragma unroll
                for (int j = 0; j < 3; j++)
                    acc[i][j] += ka[i].x * va[j].x + ka[i].y * va[j].y
                               + ka[i].z * va[j].z + ka[i].w * va[j].w;
            if (eg == 0) {
                #pragma unroll
                for (int i = 0; i < 3; i++) ks[i] += ka[i].x + ka[i].y + ka[i].z + ka[i].w;
            }
        }
    }
    float* kvp = kv + (long)bh * HDIM * HDIM;
    #pragma unroll
    for (int i = 0; i < 3; i++)
        #pragma unroll
        for (int j = 0; j < 3; j++)
            atomicAdd(&kvp[(dg * 3 + i) * HDIM + eg * 3 + j], acc[i][j]);
    if (eg == 0) {
        #pragma unroll
        for (int i = 0; i < 3; i++) atomicAdd(&ksum[bh * HDIM + dg * 3 + i], ks[i]);
    }
}

// ---------------------------------------------------------------------------
// Attention output: out[n,e] = (sum_d qp[n,d]*kv[d,e]) / (qp[n,:].ksum + 1e-6)
// grid = (49 n-tiles, 64 bh); 64 pixels/tile, thread owns (nn, 12 e's).
// ---------------------------------------------------------------------------
__global__ __launch_bounds__(256) void attn_out_k(const float* __restrict__ qpb,
                                                  const float* __restrict__ kv,
                                                  const float* __restrict__ ksum,
                                                  float* __restrict__ outb)
{
    const int bh = blockIdx.y;
    const int b = bh >> 3, h = bh & 7;
    const int n0 = blockIdx.x << 6;
    const float* qp = qpb  + (long)b * CDIM * NPIX + (long)h * HDIM * NPIX;
    float*       op = outb + (long)b * CDIM * NPIX + (long)h * HDIM * NPIX;
    __shared__ float qt[HDIM * 65];
    __shared__ float kvs[HDIM * HDIM];
    __shared__ float kss[HDIM];
    const int t = threadIdx.x;
    for (int idx = t; idx < HDIM * 64; idx += 256) {
        const int d = idx >> 6, nn = idx & 63;
        qt[d * 65 + nn] = qp[(long)d * NPIX + n0 + nn];
    }
    for (int idx = t; idx < HDIM * HDIM; idx += 256) kvs[idx] = kv[(long)bh * HDIM * HDIM + idx];
    if (t < HDIM) kss[t] = ksum[bh * HDIM + t];
    __syncthreads();
    const int nn = t & 63, eg = t >> 6;   // e = eg*12 + 0..11
    float acc[12] = {};
    float dot = 0.f;
    for (int d = 0; d < HDIM; d++) {
        const float qd = qt[d * 65 + nn];
        dot = fmaf(qd, kss[d], dot);
        const float* kr = &kvs[d * HDIM + eg * 12];
        #pragma unroll
        for (int e = 0; e < 12; e++) acc[e] = fmaf(qd, kr[e], acc[e]);
    }
    const float z = 1.f / (dot + 1e-6f);
    #pragma unroll
    for (int e = 0; e < 12; e++)
        op[(long)(eg * 12 + e) * NPIX + n0 + nn] = acc[e] * z;
}

// ---------------------------------------------------------------------------
// LayerNorm over channels + transpose NCHW -> (b*N, C) row-major.
// 32 pixels per block; stats via 8-lane shuffle groups.
// ---------------------------------------------------------------------------
__global__ __launch_bounds__(256) void ln_kernel(const float* __restrict__ x2,
                                                 const float* __restrict__ lw,
                                                 const float* __restrict__ lb,
                                                 float* __restrict__ xn)
{
    __shared__ float tile[CDIM * 33];   // [c][p], pad to 33
    __shared__ float mu_s[32], rs_s[32];
    const long g = (long)blockIdx.x * 32;
    const int b = (int)(g / NPIX);
    const int n0 = (int)(g % NPIX);
    const float* xp = x2 + (long)b * CDIM * NPIX + n0;
    const int t = threadIdx.x;
    for (int idx = t; idx < CDIM * 32; idx += 256) {
        const int c = idx >> 5, p = idx & 31;
        tile[c * 33 + p] = xp[(long)c * NPIX + p];
    }
    __syncthreads();
    {
        const int p = t >> 3, ts = t & 7;
        float sum = 0.f, sq = 0.f;
        for (int c = ts; c < CDIM; c += 8) {
            const float v = tile[c * 33 + p];
            sum += v; sq = fmaf(v, v, sq);
        }
        sum += __shfl_xor(sum, 1); sq += __shfl_xor(sq, 1);
        sum += __shfl_xor(sum, 2); sq += __shfl_xor(sq, 2);
        sum += __shfl_xor(sum, 4); sq += __shfl_xor(sq, 4);
        if (ts == 0) {
            const float mu = sum * (1.f / CDIM);
            const float var = sq * (1.f / CDIM) - mu * mu;
            mu_s[p] = mu;
            rs_s[p] = rsqrtf(var + LN_EPS);
        }
    }
    __syncthreads();
    float* op = xn + g * CDIM;
    for (int idx = t; idx < 32 * CDIM; idx += 256) {
        const int p = idx / CDIM, c = idx % CDIM;
        op[idx] = (tile[c * 33 + p] - mu_s[p]) * rs_s[p] * lw[c] + lb[c];
    }
}

// ---------------------------------------------------------------------------
// d_out[(b*C+c)*N + n] += mlp[(b*N+n)*C + c]   (64x64 LDS transpose tiles)
// ---------------------------------------------------------------------------
__global__ __launch_bounds__(256) void trans_add(const float* __restrict__ mlp,
                                                 float* __restrict__ out)
{
    __shared__ float tile[64 * 65];
    const int n0 = blockIdx.x << 6, c0 = blockIdx.y << 6, b = blockIdx.z;
    const int t = threadIdx.x;
    const float* ip = mlp + ((long)b * NPIX + n0) * CDIM + c0;
    for (int idx = t; idx < 4096; idx += 256) {
        const int nn = idx >> 6, cc = idx & 63;
        tile[nn * 65 + cc] = ip[(long)nn * CDIM + cc];
    }
    __syncthreads();
    float* op = out + ((long)b * CDIM + c0) * NPIX + n0;
    for (int idx = t; idx < 4096; idx += 256) {
        const int cc = idx >> 6, nn = idx & 63;
        op[(long)cc * NPIX + nn] += tile[nn * 65 + cc];
    }
}

// ---------------------------------------------------------------------------
// Launch
// ---------------------------------------------------------------------------
extern "C" void kernel_launch(void* const* d_in, const int* in_sizes, int n_in,
                              void* d_out, int out_size, void* d_ws, size_t ws_size,
                              hipStream_t stream)
{
    const float* x      = (const float*)d_in[0];
    const float* bn1_w  = (const float*)d_in[1];
    const float* bn1_b  = (const float*)d_in[2];
    const float* bn1_m  = (const float*)d_in[3];
    const float* bn1_v  = (const float*)d_in[4];
    const float* cw1    = (const float*)d_in[5];
    const float* cb1    = (const float*)d_in[6];
    const float* dwW    = (const float*)d_in[7];
    const float* db     = (const float*)d_in[8];
    const float* bn2_w  = (const float*)d_in[9];
    const float* bn2_b  = (const float*)d_in[10];
    const float* bn2_m  = (const float*)d_in[11];
    const float* bn2_v  = (const float*)d_in[12];
    const float* cw2    = (const float*)d_in[13];
    const float* cb2    = (const float*)d_in[14];
    const float* qkv_w  = (const float*)d_in[15];
    const float* proj_w = (const float*)d_in[16];
    const float* proj_b = (const float*)d_in[17];
    const float* ln_w   = (const float*)d_in[18];
    const float* ln_b   = (const float*)d_in[19];
    const float* mlp_w1 = (const float*)d_in[20];
    const float* mlp_b1 = (const float*)d_in[21];
    const float* mlp_w2 = (const float*)d_in[22];
    const float* mlp_b2 = (const float*)d_in[23];
    float* outF = (float*)d_out;

    const long S  = (long)BB * CDIM * NPIX;   // 9,633,792 floats per (B,C,H,W) tensor
    const long CN = (long)CDIM * NPIX;        // per-batch plane

    // Workspace map (4 big slots + small): 156 MB total.
    float* ws    = (float*)d_ws;
    float* slotA = ws;            // h -> x1 -> xn -> (free)
    float* slotB = ws + S;        // dw -> attn_out -> mlp_out
    float* slotC = ws + 2 * S;    // q(phi) ; later hmid (spans C..D, 2S)
    float* slotD = ws + 3 * S;    // k(phi)
    float* w1e = ws + 4 * S;                  // 384*384
    float* w2e = w1e + CDIM * CDIM;
    float* b1e = w2e + CDIM * CDIM;
    float* b2e = b1e + CDIM;
    float* s1  = b2e + CDIM;
    float* t1  = s1 + CDIM;
    float* s2  = t1 + CDIM;
    float* t2  = s2 + CDIM;
    float* kvb = t2 + CDIM;                   // 64*48*48
    float* ksb = kvb + 64 * HDIM * HDIM;      // 64*48

    // 0. fold BN1/BN2(+db) into conv1/conv2
    prep_bn_k<<<1, CDIM, 0, stream>>>(bn1_w, bn1_b, bn1_m, bn1_v,
                                      bn2_w, bn2_b, bn2_m, bn2_v, db, s1, t1, s2, t2);
    prep_w_k<<<2 * CDIM, 64, 0, stream>>>(cw1, cb1, cw2, cb2, s1, t1, s2, t2,
                                          w1e, b1e, w2e, b2e);

    const dim3 g49(49, 6, 8);   // (n-tiles, m-tiles, batch)
    // 1. h = W1' x + b1'           -> slotA
    gemm64<0, 1, false><<<g49, 256, 0, stream>>>(w1e, x, slotA, nullptr, b1e,
                                                 CN, CN, 0, CDIM, CDIM, NPIX, NPIX);
    // 2. d = dwconv(h)             -> slotB
    dwconv<<<BB * CDIM, 256, 0, stream>>>(slotA, dwW, slotB);
    // 3. x1 = W2' d + b2' + x      -> slotA
    gemm64<0, 1, true><<<g49, 256, 0, stream>>>(w2e, slotB, slotA, x, b2e,
                                                CN, CN, CN, CDIM, CDIM, NPIX, NPIX);
    // 4. qp = phi(Wq x1) -> slotC ; kp = phi(Wk x1) -> slotD ; v -> d_out (parked)
    gemm64<1, 0, false><<<g49, 256, 0, stream>>>(qkv_w, slotA, slotC, nullptr, nullptr,
                                                 CN, CN, 0, CDIM, CDIM, NPIX, NPIX);
    gemm64<1, 0, false><<<g49, 256, 0, stream>>>(qkv_w + CDIM * CDIM, slotA, slotD, nullptr, nullptr,
                                                 CN, CN, 0, CDIM, CDIM, NPIX, NPIX);
    gemm64<0, 0, false><<<g49, 256, 0, stream>>>(qkv_w + 2 * CDIM * CDIM, slotA, outF, nullptr, nullptr,
                                                 CN, CN, 0, CDIM, CDIM, NPIX, NPIX);
    // 5. kv / ksum  (zero then atomic-accumulate over 8 n-splits)
    hipMemsetAsync(kvb, 0, (size_t)(64 * HDIM * HDIM + 64 * HDIM) * sizeof(float), stream);
    attn_kv_k<<<dim3(8, 64), 256, 0, stream>>>(slotD, outF, kvb, ksb);
    // 6. attn_out                  -> slotB
    attn_out_k<<<dim3(49, 64), 256, 0, stream>>>(slotC, kvb, ksb, slotB);
    // 7. x2 = Wp attn + pb + x1    -> d_out (overwrites parked v)
    gemm64<0, 1, true><<<g49, 256, 0, stream>>>(proj_w, slotB, outF, slotA, proj_b,
                                                CN, CN, CN, CDIM, CDIM, NPIX, NPIX);
    // 8. xn = LN(x2), transposed to (b*N, C)  -> slotA
    ln_kernel<<<(BB * NPIX) / 32, 256, 0, stream>>>(outF, ln_w, ln_b, slotA);
    // 9. MLP in two row-halves (hmid = 12544x1536 fits exactly in slots C..D)
    const long RH = (long)(BB * NPIX / 2);   // 12544 rows
    gemm64<2, 2, false><<<dim3(24, 196, 1), 256, 0, stream>>>(slotA, mlp_w1, slotC, nullptr, mlp_b1,
                                                              0, 0, 0, CDIM, CDIM, CMID, CMID);
    gemm64<0, 2, false><<<dim3(6, 196, 1), 256, 0, stream>>>(slotC, mlp_w2, slotB, nullptr, mlp_b2,
                                                             0, 0, 0, CMID, CMID, CDIM, CDIM);
    gemm64<2, 2, false><<<dim3(24, 196, 1), 256, 0, stream>>>(slotA + RH * CDIM, mlp_w1, slotC, nullptr, mlp_b1,
                                                              0, 0, 0, CDIM, CDIM, CMID, CMID);
    gemm64<0, 2, false><<<dim3(6, 196, 1), 256, 0, stream>>>(slotC, mlp_w2, slotB + RH * CDIM, nullptr, mlp_b2,
                                                             0, 0, 0, CMID, CMID, CDIM, CDIM);
    // 10. d_out += transpose(mlp_out)
    trans_add<<<g49, 256, 0, stream>>>(slotB, outF);
}

// Round 2
// 719.562 us; speedup vs baseline: 2.5619x; 2.5619x over previous
//
#include <hip/hip_runtime.h>

#define CDIM 384
#define NPIX 3136          // 56*56
#define BB 8
#define NROW (BB * NPIX)   // 25088
#define HDIM 48
#define CMID 1536
#define BN_EPS 1e-5f
#define LN_EPS 1e-5f

typedef short s16x8 __attribute__((ext_vector_type(8)));
typedef float f32x4 __attribute__((ext_vector_type(4)));
typedef unsigned short u16;

// ---------------------------------------------------------------------------
// bf16 <-> f32 (RNE), raw ushort storage so MFMA frags are plain short8
// ---------------------------------------------------------------------------
__device__ __forceinline__ u16 f2bf(float f) {
    unsigned u = __builtin_bit_cast(unsigned, f);
    u = (u + 0x7FFFu + ((u >> 16) & 1u)) >> 16;
    return (u16)u;
}
__device__ __forceinline__ float bf2f(u16 h) {
    unsigned u = ((unsigned)h) << 16;
    return __builtin_bit_cast(float, u);
}
__device__ __forceinline__ float phi_act(float v) { return expf(0.5f * (2.f * v - v * v)); }
__device__ __forceinline__ float gelu_act(float v) { return 0.5f * v * (1.f + erff(v * 0.7071067811865476f)); }

#define GLL16(g, l) __builtin_amdgcn_global_load_lds( \
    (const __attribute__((address_space(1))) void*)(g), \
    (__attribute__((address_space(3))) void*)(l), 16, 0, 0)

// ---------------------------------------------------------------------------
// bf16 MFMA GEMM:  C(MxN) = act( A(MxK) * Bw(NxK)^T + bias ) [+ res]
// A, Bw row-major K-contiguous bf16.  128x128 tile, BK=32, 256 thr = 4 waves
// in 2x2; each wave 64x64 via 4x4 frags of 16x16x32.
// LDS layout: 16B chunks; chunk idx = group(16 rows)*64 + kquad*16 + row15,
// so frag ds_read is base + lane*16 (conflict-free) and staging is
// global_load_lds (lane l -> row g*16+(l&15), k-octet l>>4).
// ---------------------------------------------------------------------------
template<int ACT, bool BIAS, bool RES, bool OBF, bool OF32>
__global__ __launch_bounds__(256) void gemm_mfma(
    const u16* __restrict__ A, const u16* __restrict__ Bw,
    u16* __restrict__ Cbf, float* __restrict__ Cf,
    const float* __restrict__ res, const float* __restrict__ bias,
    int N, int K)
{
    __shared__ __align__(16) u16 Asb[4096];   // 8 KB
    __shared__ __align__(16) u16 Bsb[4096];
    const int t  = threadIdx.x;
    const int wv = t >> 6, ln = t & 63;
    const int lm = ln & 15, lq = ln >> 4;
    const int wm = wv >> 1, wn = wv & 1;
    const int m0 = blockIdx.y << 7, n0 = blockIdx.x << 7;

    const u16* gA0 = A  + (long)(m0 + wv * 16 + lm) * K + lq * 8;
    const u16* gA1 = gA0 + (long)64 * K;
    const u16* gB0 = Bw + (long)(n0 + wv * 16 + lm) * K + lq * 8;
    const u16* gB1 = gB0 + (long)64 * K;
    u16* lA0 = Asb + wv * 512;   // wave-uniform LDS bases (HW adds lane*16B)
    u16* lA1 = lA0 + 2048;
    u16* lB0 = Bsb + wv * 512;
    u16* lB1 = lB0 + 2048;

    f32x4 acc[4][4] = {};

    for (int k0 = 0; k0 < K; k0 += 32) {
        __syncthreads();                     // prev readers done
        GLL16(gA0, lA0); GLL16(gA1, lA1);
        GLL16(gB0, lB0); GLL16(gB1, lB1);
        gA0 += 32; gA1 += 32; gB0 += 32; gB1 += 32;
        __syncthreads();                     // drains vmcnt + barrier
        s16x8 av[4], bv[4];
        #pragma unroll
        for (int mf = 0; mf < 4; mf++)
            av[mf] = *(const s16x8*)&Asb[(wm * 256 + mf * 64 + ln) * 8];
        #pragma unroll
        for (int nf = 0; nf < 4; nf++)
            bv[nf] = *(const s16x8*)&Bsb[(wn * 256 + nf * 64 + ln) * 8];
        #pragma unroll
        for (int mf = 0; mf < 4; mf++)
            #pragma unroll
            for (int nf = 0; nf < 4; nf++)
                acc[mf][nf] = __builtin_amdgcn_mfma_f32_16x16x32_bf16(
                    av[mf], bv[nf], acc[mf][nf], 0, 0, 0);
    }

    // Epilogue. C/D layout: col = lane&15, row = (lane>>4)*4 + reg.
    #pragma unroll
    for (int nf = 0; nf < 4; nf++) {
        const int gn = n0 + wn * 64 + nf * 16 + lm;
        const float bval = BIAS ? bias[gn] : 0.f;
        #pragma unroll
        for (int mf = 0; mf < 4; mf++) {
            const int gmb = m0 + wm * 64 + mf * 16 + lq * 4;
            #pragma unroll
            for (int r = 0; r < 4; r++) {
                float v = acc[mf][nf][r] + bval;
                if (ACT == 1) v = phi_act(v);
                else if (ACT == 2) v = gelu_act(v);
                const long off = (long)(gmb + r) * N + gn;
                if (RES) v += res[off];
                if (OF32) Cf[off] = v;
                if (OBF)  Cbf[off] = f2bf(v);
            }
        }
    }
}

// ---------------------------------------------------------------------------
// NCHW f32 -> NHWC f32 + bf16 (64x64 LDS tiles)
// ---------------------------------------------------------------------------
__global__ __launch_bounds__(256) void nchw_to_nhwc(const float* __restrict__ x,
                                                    float* __restrict__ of,
                                                    u16* __restrict__ ob)
{
    __shared__ float tile[64 * 65];
    const int n0 = blockIdx.x << 6, c0 = blockIdx.y << 6, b = blockIdx.z;
    const int t = threadIdx.x;
    const float* ip = x + ((long)b * CDIM + c0) * NPIX + n0;
    for (int idx = t; idx < 4096; idx += 256) {
        const int cc = idx >> 6, nn = idx & 63;
        tile[cc * 65 + nn] = ip[(long)cc * NPIX + nn];
    }
    __syncthreads();
    for (int idx = t; idx < 4096; idx += 256) {
        const int nn = idx >> 6, cc = idx & 63;
        const float v = tile[cc * 65 + nn];
        const long o = ((long)b * NPIX + n0 + nn) * CDIM + c0 + cc;
        of[o] = v; ob[o] = f2bf(v);
    }
}

// ---------------------------------------------------------------------------
// Depthwise 3x3 SAME, NHWC bf16. One thread per (b, pixel, 8-channel chunk).
// wt layout: [tap][c] bf16.
// ---------------------------------------------------------------------------
__global__ __launch_bounds__(256) void dwconv_nhwc(const u16* __restrict__ in,
                                                   const u16* __restrict__ wt,
                                                   u16* __restrict__ out)
{
    const long tid = (long)blockIdx.x * 256 + threadIdx.x;   // 8*3136*48
    const int c8 = (int)(tid % 48);
    const int p  = (int)((tid / 48) % NPIX);
    const int b  = (int)(tid / (48LL * NPIX));
    const int y = p / 56, x = p % 56;
    const u16* base = in + (long)b * NPIX * CDIM + c8 * 8;
    float acc[8] = {};
    #pragma unroll
    for (int r = 0; r < 3; r++) {
        const int yy = y + r - 1;
        if ((unsigned)yy >= 56u) continue;
        #pragma unroll
        for (int s = 0; s < 3; s++) {
            const int xx = x + s - 1;
            if ((unsigned)xx >= 56u) continue;
            const s16x8 iv = *(const s16x8*)&base[(long)(yy * 56 + xx) * CDIM];
            const s16x8 wv = *(const s16x8*)&wt[(r * 3 + s) * CDIM + c8 * 8];
            #pragma unroll
            for (int j = 0; j < 8; j++)
                acc[j] = fmaf(bf2f((u16)iv[j]), bf2f((u16)wv[j]), acc[j]);
        }
    }
    s16x8 ov;
    #pragma unroll
    for (int j = 0; j < 8; j++) ov[j] = (short)f2bf(acc[j]);
    *(s16x8*)&out[((long)b * NPIX + p) * CDIM + c8 * 8] = ov;
}

// ---------------------------------------------------------------------------
// kv[bh][d][e] = sum_n kp*v ; ksum[bh][d] = sum_n kp.  NHWC bf16 inputs.
// qk: (NROW,768) q|k ; v: (NROW,384). grid(8 splits, 64 bh), atomic finish.
// ---------------------------------------------------------------------------
__global__ __launch_bounds__(256) void attn_kv_k(const u16* __restrict__ qk,
                                                 const u16* __restrict__ vb,
                                                 float* __restrict__ kv,
                                                 float* __restrict__ ksum)
{
    const int sp = blockIdx.x, bh = blockIdx.y;
    const int b = bh >> 3, h = bh & 7;
    const u16* kbase = qk + (long)b * NPIX * 768 + 384 + h * HDIM;
    const u16* vbase = vb + (long)b * NPIX * CDIM + h * HDIM;
    __shared__ float kt[64 * 48];
    __shared__ float vt[64 * 48];
    const int t = threadIdx.x;
    const int dg = t >> 4, eg = t & 15;
    float acc[3][3] = {};
    float ks[3] = {};
    for (int tl = sp; tl < 49; tl += 8) {
        const int n0 = tl << 6;
        __syncthreads();
        for (int idx = t; idx < 3072; idx += 256) {
            const int nn = idx / 48, d = idx % 48;
            kt[idx] = bf2f(kbase[(long)(n0 + nn) * 768 + d]);
            vt[idx] = bf2f(vbase[(long)(n0 + nn) * CDIM + d]);
        }
        __syncthreads();
        for (int nn = 0; nn < 64; nn++) {
            float kvv[3], vvv[3];
            #pragma unroll
            for (int i = 0; i < 3; i++) kvv[i] = kt[nn * 48 + dg * 3 + i];
            #pragma unroll
            for (int j = 0; j < 3; j++) vvv[j] = vt[nn * 48 + eg * 3 + j];
            #pragma unroll
            for (int i = 0; i < 3; i++)
                #pragma unroll
                for (int j = 0; j < 3; j++)
                    acc[i][j] = fmaf(kvv[i], vvv[j], acc[i][j]);
            if (eg == 0) {
                #pragma unroll
                for (int i = 0; i < 3; i++) ks[i] += kvv[i];
            }
        }
    }
    float* kvp = kv + (long)bh * HDIM * HDIM;
    #pragma unroll
    for (int i = 0; i < 3; i++)
        #pragma unroll
        for (int j = 0; j < 3; j++)
            atomicAdd(&kvp[(dg * 3 + i) * HDIM + eg * 3 + j], acc[i][j]);
    if (eg == 0) {
        #pragma unroll
        for (int i = 0; i < 3; i++) atomicAdd(&ksum[bh * HDIM + dg * 3 + i], ks[i]);
    }
}

// ---------------------------------------------------------------------------
// out[n][h*48+e] = (sum_d qp*kv) / (qp . ksum + eps).  bf16 out (NROW,384).
// ---------------------------------------------------------------------------
__global__ __launch_bounds__(256) void attn_out_k(const u16* __restrict__ qk,
                                                  const float* __restrict__ kv,
                                                  const float* __restrict__ ksum,
                                                  u16* __restrict__ outb)
{
    const int bh = blockIdx.y, b = bh >> 3, h = bh & 7;
    const int n0 = blockIdx.x << 6;
    const u16* qbase = qk + (long)b * NPIX * 768 + h * HDIM;
    __shared__ float qt[64 * 48];
    __shared__ float kvs[48 * 48];
    __shared__ float kss[48];
    const int t = threadIdx.x;
    for (int idx = t; idx < 3072; idx += 256) {
        const int nn = idx / 48, d = idx % 48;
        qt[idx] = bf2f(qbase[(long)(n0 + nn) * 768 + d]);
    }
    for (int idx = t; idx < 2304; idx += 256) kvs[idx] = kv[(long)bh * HDIM * HDIM + idx];
    if (t < 48) kss[t] = ksum[bh * HDIM + t];
    __syncthreads();
    const int nn = t & 63, eg = t >> 6;
    float a[12] = {};
    float dot = 0.f;
    for (int d = 0; d < 48; d++) {
        const float qd = qt[nn * 48 + d];
        dot = fmaf(qd, kss[d], dot);
        const float* kr = &kvs[d * 48 + eg * 12];
        #pragma unroll
        for (int e = 0; e < 12; e++) a[e] = fmaf(qd, kr[e], a[e]);
    }
    const float z = 1.f / (dot + 1e-6f);
    u16* op = outb + ((long)b * NPIX + n0 + nn) * CDIM + h * HDIM + eg * 12;
    #pragma unroll
    for (int e = 0; e < 12; e++) op[e] = f2bf(a[e] * z);
}

// ---------------------------------------------------------------------------
// LayerNorm over contiguous 384 channels (NHWC). 4 rows/block, 1 wave/row.
// ---------------------------------------------------------------------------
__global__ __launch_bounds__(256) void ln_k(const float* __restrict__ x2,
                                            const float* __restrict__ lw,
                                            const float* __restrict__ lb,
                                            u16* __restrict__ xn)
{
    const int row = blockIdx.x * 4 + (threadIdx.x >> 6);
    const int lane = threadIdx.x & 63;
    const float* rp = x2 + (long)row * CDIM;
    float2 v[3];
    float sum = 0.f, sq = 0.f;
    #pragma unroll
    for (int i = 0; i < 3; i++) {
        v[i] = *(const float2*)&rp[lane * 2 + i * 128];
        sum += v[i].x + v[i].y;
        sq = fmaf(v[i].x, v[i].x, fmaf(v[i].y, v[i].y, sq));
    }
    #pragma unroll
    for (int off = 1; off < 64; off <<= 1) {
        sum += __shfl_xor(sum, off);
        sq  += __shfl_xor(sq, off);
    }
    const float mu = sum * (1.f / CDIM);
    const float rs = rsqrtf(sq * (1.f / CDIM) - mu * mu + LN_EPS);
    u16* op = xn + (long)row * CDIM;
    #pragma unroll
    for (int i = 0; i < 3; i++) {
        const int c = lane * 2 + i * 128;
        op[c]     = f2bf((v[i].x - mu) * rs * lw[c] + lb[c]);
        op[c + 1] = f2bf((v[i].y - mu) * rs * lw[c + 1] + lb[c + 1]);
    }
}

// ---------------------------------------------------------------------------
// d_out NCHW = transpose(x2 + mlp) from NHWC f32
// ---------------------------------------------------------------------------
__global__ __launch_bounds__(256) void final_out(const float* __restrict__ x2,
                                                 const float* __restrict__ mlp,
                                                 float* __restrict__ out)
{
    __shared__ float tile[64 * 65];
    const int n0 = blockIdx.x << 6, c0 = blockIdx.y << 6, b = blockIdx.z;
    const int t = threadIdx.x;
    for (int idx = t; idx < 4096; idx += 256) {
        const int nn = idx >> 6, cc = idx & 63;
        const long o = ((long)b * NPIX + n0 + nn) * CDIM + c0 + cc;
        tile[nn * 65 + cc] = x2[o] + mlp[o];
    }
    __syncthreads();
    float* op = out + ((long)b * CDIM + c0) * NPIX + n0;
    for (int idx = t; idx < 4096; idx += 256) {
        const int cc = idx >> 6, nn = idx & 63;
        op[(long)cc * NPIX + nn] = tile[nn * 65 + cc];
    }
}

// ---------------------------------------------------------------------------
// Prep kernels
// ---------------------------------------------------------------------------
__global__ void prep_bn_k(const float* __restrict__ w1, const float* __restrict__ b1,
                          const float* __restrict__ m1, const float* __restrict__ v1,
                          const float* __restrict__ w2, const float* __restrict__ b2,
                          const float* __restrict__ m2, const float* __restrict__ v2,
                          const float* __restrict__ db,
                          float* s1, float* t1, float* s2, float* t2)
{
    const int i = threadIdx.x;
    if (i < CDIM) {
        const float a = w1[i] * rsqrtf(v1[i] + BN_EPS);
        s1[i] = a; t1[i] = b1[i] - m1[i] * a;
        const float c = w2[i] * rsqrtf(v2[i] + BN_EPS);
        s2[i] = c; t2[i] = b2[i] - m2[i] * c + db[i] * c;
    }
}

__global__ __launch_bounds__(64) void prep_w_k(
    const float* __restrict__ cw1, const float* __restrict__ cb1,
    const float* __restrict__ cw2, const float* __restrict__ cb2,
    const float* __restrict__ s1, const float* __restrict__ t1,
    const float* __restrict__ s2, const float* __restrict__ t2,
    u16* __restrict__ w1e, float* __restrict__ b1e,
    u16* __restrict__ w2e, float* __restrict__ b2e)
{
    const int o = blockIdx.x;
    const bool sec = (o >= CDIM);
    const int oo = sec ? o - CDIM : o;
    const float* cw = sec ? cw2 : cw1;
    const float* cb = sec ? cb2 : cb1;
    const float* s  = sec ? s2  : s1;
    const float* tt = sec ? t2  : t1;
    u16* we = sec ? w2e : w1e;
    float* be = sec ? b2e : b1e;
    float part = 0.f;
    for (int i = threadIdx.x; i < CDIM; i += 64) {
        const float wv = cw[oo * CDIM + i];
        we[oo * CDIM + i] = f2bf(wv * s[i]);
        part += wv * tt[i];
    }
    for (int off = 32; off; off >>= 1) part += __shfl_down(part, off);
    if (threadIdx.x == 0) be[oo] = cb[oo] + part;
}

__global__ void cvt_k(const float* __restrict__ in, u16* __restrict__ out, int n)
{
    const int i = blockIdx.x * 256 + threadIdx.x;
    if (i < n) out[i] = f2bf(in[i]);
}

// out[c][r] = bf16(in[r][c]); in (R,C) f32, grid (C/64, R/64)
__global__ __launch_bounds__(256) void transcvt_k(const float* __restrict__ in,
                                                  u16* __restrict__ out, int R, int C)
{
    __shared__ float tile[64 * 65];
    const int c0 = blockIdx.x << 6, r0 = blockIdx.y << 6;
    const int t = threadIdx.x;
    for (int idx = t; idx < 4096; idx += 256) {
        const int rr = idx >> 6, cc = idx & 63;
        tile[rr * 65 + cc] = in[(long)(r0 + rr) * C + c0 + cc];
    }
    __syncthreads();
    for (int idx = t; idx < 4096; idx += 256) {
        const int cc = idx >> 6, rr = idx & 63;
        out[(long)(c0 + cc) * R + r0 + rr] = f2bf(tile[rr * 65 + cc]);
    }
}

__global__ void dwt_k(const float* __restrict__ dw, u16* __restrict__ o)
{
    const int i = blockIdx.x * 256 + threadIdx.x;
    if (i < 9 * CDIM) {
        const int c = i / 9, tap = i % 9;
        o[tap * CDIM + c] = f2bf(dw[i]);
    }
}

// ---------------------------------------------------------------------------
// Launch
// ---------------------------------------------------------------------------
extern "C" void kernel_launch(void* const* d_in, const int* in_sizes, int n_in,
                              void* d_out, int out_size, void* d_ws, size_t ws_size,
                              hipStream_t stream)
{
    const float* x      = (const float*)d_in[0];
    const float* bn1_w  = (const float*)d_in[1];
    const float* bn1_b  = (const float*)d_in[2];
    const float* bn1_m  = (const float*)d_in[3];
    const float* bn1_v  = (const float*)d_in[4];
    const float* cw1    = (const float*)d_in[5];
    const float* cb1    = (const float*)d_in[6];
    const float* dwW    = (const float*)d_in[7];
    const float* db     = (const float*)d_in[8];
    const float* bn2_w  = (const float*)d_in[9];
    const float* bn2_b  = (const float*)d_in[10];
    const float* bn2_m  = (const float*)d_in[11];
    const float* bn2_v  = (const float*)d_in[12];
    const float* cw2    = (const float*)d_in[13];
    const float* cb2    = (const float*)d_in[14];
    const float* qkv_w  = (const float*)d_in[15];
    const float* proj_w = (const float*)d_in[16];
    const float* proj_b = (const float*)d_in[17];
    const float* ln_w   = (const float*)d_in[18];
    const float* ln_b   = (const float*)d_in[19];
    const float* mlp_w1 = (const float*)d_in[20];
    const float* mlp_b1 = (const float*)d_in[21];
    const float* mlp_w2 = (const float*)d_in[22];
    const float* mlp_b2 = (const float*)d_in[23];
    float* outF = (float*)d_out;

    const long S = (long)NROW * CDIM;   // 9,633,792
    float* wsf = (float*)d_ws;

    // fp32 slots (time-aliased)
    float* xh_f  = wsf;                       // F0: NHWC x (dead after g2)
    float* x2_f  = wsf;                       // F0: x2 (born g4)
    u16*   v_bf  = (u16*)wsf;                 // F0 during attention (v, 1U)
    float* x1_f  = wsf + S;                   // F1: x1 (dead after g4)
    u16*   hmid  = (u16*)(wsf + S);           // F1: mlp hidden half (2U halfs)
    // bf16 arena: 3U halfs starting at 2S floats
    u16* ar   = (u16*)(wsf + 2 * S);
    u16* a0   = ar;                           // xh_bf -> x1_bf -> attn_bf -> xn_bf
    u16* a1   = ar + S;                       // h_bf -> qk_bf (2U: a1..a2)
    u16* a2   = ar + 2 * S;                   // d_bf
    float* mlp_f = (float*)(ar + S);          // mlp out f32 (2U halfs = S floats)
    // weights
    u16* wtb   = (u16*)(wsf + 3 * S + S / 2);
    u16* w1e   = wtb;
    u16* w2e   = w1e + CDIM * CDIM;
    u16* qkvw  = w2e + CDIM * CDIM;           // 1152*384 (q|k rows 0..767, v 768..)
    u16* projw = qkvw + 1152 * CDIM;
    u16* mw1t  = projw + CDIM * CDIM;         // (1536,384)
    u16* mw2t  = mw1t + CMID * CDIM;          // (384,1536)
    u16* dwt   = mw2t + CDIM * CMID;          // (9,384)
    float* fb  = (float*)(dwt + 9 * CDIM);
    float* b1e = fb;
    float* b2e = b1e + CDIM;
    float* s1  = b2e + CDIM;
    float* t1  = s1 + CDIM;
    float* s2  = t1 + CDIM;
    float* t2  = s2 + CDIM;
    float* kvb = t2 + CDIM;                   // 64*48*48
    float* ksb = kvb + 64 * HDIM * HDIM;      // 64*48

    // --- weight prep ---
    prep_bn_k<<<1, CDIM, 0, stream>>>(bn1_w, bn1_b, bn1_m, bn1_v,
                                      bn2_w, bn2_b, bn2_m, bn2_v, db, s1, t1, s2, t2);
    prep_w_k<<<2 * CDIM, 64, 0, stream>>>(cw1, cb1, cw2, cb2, s1, t1, s2, t2,
                                          w1e, b1e, w2e, b2e);
    cvt_k<<<(1152 * CDIM + 255) / 256, 256, 0, stream>>>(qkv_w, qkvw, 1152 * CDIM);
    cvt_k<<<(CDIM * CDIM + 255) / 256, 256, 0, stream>>>(proj_w, projw, CDIM * CDIM);
    transcvt_k<<<dim3(CMID / 64, CDIM / 64), 256, 0, stream>>>(mlp_w1, mw1t, CDIM, CMID);
    transcvt_k<<<dim3(CDIM / 64, CMID / 64), 256, 0, stream>>>(mlp_w2, mw2t, CMID, CDIM);
    dwt_k<<<(9 * CDIM + 255) / 256, 256, 0, stream>>>(dwW, dwt);

    // --- pipeline (all NHWC) ---
    nchw_to_nhwc<<<dim3(49, 6, 8), 256, 0, stream>>>(x, xh_f, a0);
    // g1: h = conv1(x)
    gemm_mfma<0, true, false, true, false><<<dim3(3, 196), 256, 0, stream>>>(
        a0, w1e, a1, nullptr, nullptr, b1e, CDIM, CDIM);
    dwconv_nhwc<<<(int)((long)BB * NPIX * 48 / 256), 256, 0, stream>>>(a1, dwt, a2);
    // g2: x1 = conv2(d) + x   (bf16 + f32 outputs)
    gemm_mfma<0, true, true, true, true><<<dim3(3, 196), 256, 0, stream>>>(
        a2, w2e, a0, x1_f, xh_f, b2e, CDIM, CDIM);
    // g3a: qk = phi(Wqk x1) ; g3b: v = Wv x1
    gemm_mfma<1, false, false, true, false><<<dim3(6, 196), 256, 0, stream>>>(
        a0, qkvw, a1, nullptr, nullptr, nullptr, 768, CDIM);
    gemm_mfma<0, false, false, true, false><<<dim3(3, 196), 256, 0, stream>>>(
        a0, qkvw + 768 * CDIM, v_bf, nullptr, nullptr, nullptr, CDIM, CDIM);
    // attention
    hipMemsetAsync(kvb, 0, (size_t)(64 * HDIM * HDIM + 64 * HDIM) * sizeof(float), stream);
    attn_kv_k<<<dim3(8, 64), 256, 0, stream>>>(a1, v_bf, kvb, ksb);
    attn_out_k<<<dim3(49, 64), 256, 0, stream>>>(a1, kvb, ksb, a0);
    // g4: x2 = proj(attn) + x1   (f32 only)
    gemm_mfma<0, true, true, false, true><<<dim3(3, 196), 256, 0, stream>>>(
        a0, projw, nullptr, x2_f, x1_f, proj_b, CDIM, CDIM);
    // LN -> xn (bf16)
    ln_k<<<NROW / 4, 256, 0, stream>>>(x2_f, ln_w, ln_b, a0);
    // MLP in two M-halves (hmid reuses F1)
    const long RH = (long)NROW / 2;   // 12544
    gemm_mfma<2, true, false, true, false><<<dim3(12, 98), 256, 0, stream>>>(
        a0, mw1t, hmid, nullptr, nullptr, mlp_b1, CMID, CDIM);
    gemm_mfma<0, true, false, false, true><<<dim3(3, 98), 256, 0, stream>>>(
        hmid, mw2t, nullptr, mlp_f, nullptr, mlp_b2, CDIM, CMID);
    gemm_mfma<2, true, false, true, false><<<dim3(12, 98), 256, 0, stream>>>(
        a0 + RH * CDIM, mw1t, hmid, nullptr, nullptr, mlp_b1, CMID, CDIM);
    gemm_mfma<0, true, false, false, true><<<dim3(3, 98), 256, 0, stream>>>(
        hmid, mw2t, nullptr, mlp_f + RH * CDIM, nullptr, mlp_b2, CDIM, CMID);
    // final: d_out = NCHW(x2 + mlp)
    final_out<<<dim3(49, 6, 8), 256, 0, stream>>>(x2_f, mlp_f, outF);
}